// Round 7
// baseline (495.968 us; speedup 1.0000x reference)
//
#include <hip/hip_runtime.h>
#include <hip/hip_bf16.h>

#define T_SEQ 2048
#define DMODEL 1024
#define NHEAD 16
#define DHEAD 64
#define NBATCH 2
#define NROWS (NBATCH * T_SEQ)   // 4096
#define DFFN (4 * DMODEL)        // 4096
#define S1 3072                  // fused [Qc|Kc|V] row stride
#define S2 2048                  // fused [Qs|Ks] row stride
// softmax scale folded into Q projection: (1/sqrt(64)) * log2(e)
#define QSCALE 0.18033688011112042f

typedef __bf16 bf16;
typedef __bf16 bf16x8 __attribute__((ext_vector_type(8)));
typedef __bf16 bf16x4 __attribute__((ext_vector_type(4)));
typedef float f32x4 __attribute__((ext_vector_type(4)));

__device__ __forceinline__ void gload_lds16(const void* g, void* l) {
    __builtin_amdgcn_global_load_lds((const __attribute__((address_space(1))) unsigned int*)g,
                                     (__attribute__((address_space(3))) unsigned int*)l, 16, 0, 0);
}

// ---------------------------------------------------------------- fused 6x [1024][1024] f32 -> bf16 transpose
struct TP6 { const float* src[6]; bf16* dst[6]; };
__global__ void transpose6(TP6 p) {
    __shared__ float tile[32][33];
    const float* in = p.src[blockIdx.z];
    bf16* out = p.dst[blockIdx.z];
    int k0 = blockIdx.y * 32, n0 = blockIdx.x * 32;
    int tx = threadIdx.x & 31, ty = threadIdx.x >> 5;
#pragma unroll
    for (int i = 0; i < 32; i += 8)
        tile[ty + i][tx] = in[(size_t)(k0 + ty + i) * 1024 + n0 + tx];
    __syncthreads();
#pragma unroll
    for (int i = 0; i < 32; i += 8)
        out[(size_t)(n0 + ty + i) * 1024 + k0 + tx] = (bf16)tile[tx][ty + i];
}

__global__ void transpose_f32_to_bf16(const float* __restrict__ in, bf16* __restrict__ out,
                                      int K, int N) {
    __shared__ float tile[32][33];
    int k0 = blockIdx.y * 32, n0 = blockIdx.x * 32;
    int tx = threadIdx.x & 31, ty = threadIdx.x >> 5;
#pragma unroll
    for (int i = 0; i < 32; i += 8)
        tile[ty + i][tx] = in[(size_t)(k0 + ty + i) * N + n0 + tx];
    __syncthreads();
#pragma unroll
    for (int i = 0; i < 32; i += 8)
        out[(size_t)(n0 + ty + i) * K + k0 + tx] = (bf16)tile[tx][ty + i];
}

__global__ void cast_f32_bf16(const float* __restrict__ in, bf16* __restrict__ out, int n4) {
    int i = blockIdx.x * blockDim.x + threadIdx.x;
    if (i >= n4) return;
    float4 v = reinterpret_cast<const float4*>(in)[i];
    bf16x4 o;
    o[0] = (bf16)v.x; o[1] = (bf16)v.y; o[2] = (bf16)v.z; o[3] = (bf16)v.w;
    reinterpret_cast<bf16x4*>(out)[i] = o;
}

__global__ void concat_bias3(const float* __restrict__ b0, const float* __restrict__ b1,
                             const float* __restrict__ b2, float* __restrict__ out, int n) {
    int i = blockIdx.x * 256 + threadIdx.x;
    if (i >= n) return;
    const float* src = (i < 1024) ? b0 : (i < 2048) ? b1 : b2;
    out[i] = src[i & 1023];
}

// ---------------------------------------------------------------- LayerNorm row (D=1024), out bf16
__global__ void layernorm_bf16(const float* __restrict__ x, const float* __restrict__ w,
                               const float* __restrict__ b, bf16* __restrict__ out) {
    int row = blockIdx.x;
    int t = threadIdx.x;
    const float* xr = x + (size_t)row * DMODEL;
    float4 v = reinterpret_cast<const float4*>(xr)[t];
    float s = v.x + v.y + v.z + v.w;
    float sq = v.x * v.x + v.y * v.y + v.z * v.z + v.w * v.w;
#pragma unroll
    for (int off = 1; off < 64; off <<= 1) {
        s += __shfl_xor(s, off);
        sq += __shfl_xor(sq, off);
    }
    __shared__ float ss[4], ssq[4];
    int wid = t >> 6;
    if ((t & 63) == 0) { ss[wid] = s; ssq[wid] = sq; }
    __syncthreads();
    s = ss[0] + ss[1] + ss[2] + ss[3];
    sq = ssq[0] + ssq[1] + ssq[2] + ssq[3];
    float mu = s * (1.0f / DMODEL);
    float var = sq * (1.0f / DMODEL) - mu * mu;
    float rstd = rsqrtf(var + 1e-5f);
    float4 wv = reinterpret_cast<const float4*>(w)[t];
    float4 bv = reinterpret_cast<const float4*>(b)[t];
    bf16x4 o;
    o[0] = (bf16)((v.x - mu) * rstd * wv.x + bv.x);
    o[1] = (bf16)((v.y - mu) * rstd * wv.y + bv.y);
    o[2] = (bf16)((v.z - mu) * rstd * wv.z + bv.z);
    o[3] = (bf16)((v.w - mu) * rstd * wv.w + bv.w);
    reinterpret_cast<bf16x4*>(out + (size_t)row * DMODEL)[t] = o;
}

// ================================================================ 8-phase 256x256 GEMM (T2+T3+T4+T5)
// C[M,N] = A[M,K](bf16) * Bt[N,K](bf16)^T.  512 threads = 8 waves (2M x 4N), BK=64.
// LDS: A,B each 2 dbuf x 2 halves of [128][64] bf16, XOR-swizzled byte ^= (byte>>3)&0x70.
// MODE 0: bf16 out  MODE 1: bf16 + exact GELU.  SCALEQ: cols<1024 scaled by QSCALE.
#define SWZ(x) ((x) ^ (((x) >> 3) & 0x70))

#define PHASE(BUF, Q, VM, ...) {                                              \
    if ((Q) == 0) {                                                           \
        _Pragma("unroll") for (int nf = 0; nf < 4; nf++)                      \
        _Pragma("unroll") for (int ks = 0; ks < 2; ks++) {                    \
            int lb = (((wc & 1) * 64 + nf * 16 + l15) << 7) + ks * 64 + lg * 16; \
            bfr[nf][ks] = *(const bf16x8*)(sBh[BUF] + SWZ(lb));               \
        }                                                                     \
    }                                                                         \
    bf16x8 af[2][2];                                                          \
    _Pragma("unroll") for (int j = 0; j < 2; j++)                             \
    _Pragma("unroll") for (int ks = 0; ks < 2; ks++) {                        \
        int lb = ((((Q) * 2 + j) * 16 + l15) << 7) + ks * 64 + lg * 16;       \
        af[j][ks] = *(const bf16x8*)(sAh[BUF] + SWZ(lb));                     \
    }                                                                         \
    __VA_ARGS__;                                                              \
    if (VM) asm volatile("s_waitcnt vmcnt(4)" ::: "memory");                  \
    __builtin_amdgcn_s_barrier();                                             \
    asm volatile("s_waitcnt lgkmcnt(0)" ::: "memory");                        \
    __builtin_amdgcn_sched_barrier(0);                                        \
    __builtin_amdgcn_s_setprio(1);                                            \
    _Pragma("unroll") for (int j = 0; j < 2; j++)                             \
    _Pragma("unroll") for (int nf = 0; nf < 4; nf++)                          \
    _Pragma("unroll") for (int ks = 0; ks < 2; ks++)                          \
        acc[(Q) * 2 + j][nf] = __builtin_amdgcn_mfma_f32_16x16x32_bf16(       \
            af[j][ks], bfr[nf][ks], acc[(Q) * 2 + j][nf], 0, 0, 0);           \
    __builtin_amdgcn_s_setprio(0);                                            \
    __builtin_amdgcn_s_barrier();                                             \
}

template <int MODE, int SCALEQ>
__global__ __launch_bounds__(512, 2) void gemm_256(const bf16* __restrict__ A,
                                                   const bf16* __restrict__ Bt,
                                                   const float* __restrict__ bias,
                                                   void* __restrict__ Cout,
                                                   int M, int N, int K) {
    __shared__ __align__(16) bf16 sA[2][2][8192];  // [buf][half][128*64]
    __shared__ __align__(16) bf16 sB[2][2][8192];
    // bijective XCD swizzle (grid sizes are %8==0)
    int lin = blockIdx.y * gridDim.x + blockIdx.x;
    int cpx = (gridDim.x * gridDim.y) >> 3;
    int swz = (lin & 7) * cpx + (lin >> 3);
    int bx = swz % gridDim.x, by = swz / gridDim.x;
    int m0 = by * 256, n0 = bx * 256;
    int t = threadIdx.x, lane = t & 63, w = t >> 6;
    int wr = w >> 2, wc = w & 3;          // 2M x 4N wave grid
    int l15 = lane & 15, lg = lane >> 4;
    f32x4 acc[8][4] = {};
    bf16x8 bfr[4][2];

    const char* sAh[2] = { (const char*)&sA[0][wr][0], (const char*)&sA[1][wr][0] };
    const char* sBh[2] = { (const char*)&sB[0][wc >> 1][0], (const char*)&sB[1][wc >> 1][0] };

    // stage one [128][64] half-tile: dest linear (2 x 8KB rounds), source pre-swizzled
    auto stageA = [&](int buf, int h, int kt) {
        int kb = kt * 64;
#pragma unroll
        for (int rd = 0; rd < 2; rd++) {
            int cb = w * 64 + rd * 512;            // wave-uniform chunk base
            int d = (cb + lane) * 16;
            int lv = SWZ(d);
            int r = lv >> 7, c = (lv & 127) >> 1;
            gload_lds16(A + (size_t)(m0 + h * 128 + r) * K + kb + c,
                        (char*)&sA[buf][h][0] + cb * 16);
        }
    };
    auto stageB = [&](int buf, int h, int kt) {
        int kb = kt * 64;
#pragma unroll
        for (int rd = 0; rd < 2; rd++) {
            int cb = w * 64 + rd * 512;
            int d = (cb + lane) * 16;
            int lv = SWZ(d);
            int r = lv >> 7, c = (lv & 127) >> 1;
            gload_lds16(Bt + (size_t)(n0 + h * 128 + r) * K + kb + c,
                        (char*)&sB[buf][h][0] + cb * 16);
        }
    };

    const int NT = K / 64;
    // prologue: A(0), B(0), B(1) staged; wait A(0)+B(0) landed (B(1) = newest 4 loads outstanding)
    stageA(0, 0, 0); stageA(0, 1, 0);
    stageB(0, 0, 0); stageB(0, 1, 0);
    stageB(1, 0, 1); stageB(1, 1, 1);
    asm volatile("s_waitcnt vmcnt(4)" ::: "memory");
    __builtin_amdgcn_s_barrier();

    for (int i = 0; i < NT / 2; ++i) {
        int t0 = 2 * i;
        // --- K-tile t0 (buf0) ---
        PHASE(0, 0, 0, { stageA(1, 0, t0 + 1); stageA(1, 1, t0 + 1); })   // A(t0+1) -> bufA1 (dead since prev P8)
        PHASE(0, 1, 0, { if (t0 + 2 < NT) stageB(0, 0, t0 + 2); })        // bufB0 dead after P1
        PHASE(0, 2, 0, { if (t0 + 2 < NT) stageB(0, 1, t0 + 2); })
        PHASE(0, 3, 1, { })                                               // vmcnt(4): A(t0+1),B(t0+1) landed
        // --- K-tile t0+1 (buf1) ---
        PHASE(1, 0, 0, { if (t0 + 2 < NT) stageA(0, 0, t0 + 2); })        // bufA0 dead after P4
        PHASE(1, 1, 0, { if (t0 + 2 < NT) stageA(0, 1, t0 + 2); })
        PHASE(1, 2, 0, { if (t0 + 3 < NT) stageB(1, 0, t0 + 3); })        // bufB1 dead after P5
        PHASE(1, 3, 1, { if (t0 + 3 < NT) stageB(1, 1, t0 + 3); })        // vmcnt(4): A(t0+2),B(t0+2) landed
    }

#pragma unroll
    for (int mf = 0; mf < 8; mf++) {
#pragma unroll
        for (int nf = 0; nf < 4; nf++) {
            int col = n0 + wc * 64 + nf * 16 + l15;
            float bsv = bias[col];
#pragma unroll
            for (int r = 0; r < 4; r++) {
                int row = m0 + wr * 128 + mf * 16 + lg * 4 + r;
                float v = acc[mf][nf][r] + bsv;
                if (SCALEQ && col < 1024) v *= QSCALE;
                size_t idx = (size_t)row * N + col;
                if (MODE == 0) {
                    ((bf16*)Cout)[idx] = (bf16)v;
                } else {
                    float g = 0.5f * v * (1.0f + erff(v * 0.70710678118654752f));
                    ((bf16*)Cout)[idx] = (bf16)g;
                }
            }
        }
    }
}

// ---------------------------------------------------------------- GEMM (m97 structure, single-buffered) for N=1024 outputs
// MODE 2: f32 out = v + bias + res
template <int BN, int MODE, int SCALEQ>
__global__ __launch_bounds__(256, 3) void gemm_glds(const bf16* __restrict__ A,
                                                    const bf16* __restrict__ Bt,
                                                    const float* __restrict__ bias,
                                                    const float* __restrict__ res,
                                                    void* __restrict__ Cout,
                                                    int M, int N, int K) {
    constexpr int BM = 128, BK = 32;
    constexpr int WN = BN / 2;
    constexpr int NB = BN / 64;
    constexpr int NI = WN / 16;
    __shared__ __align__(16) bf16 As[BM * BK];
    __shared__ __align__(16) bf16 Bs[BN * BK];
    int lin = blockIdx.y * gridDim.x + blockIdx.x;
    int cpx = (gridDim.x * gridDim.y) >> 3;
    int swz = (lin & 7) * cpx + (lin >> 3);
    int bx = swz % gridDim.x, by = swz / gridDim.x;
    int m0 = by * BM, n0 = bx * BN;
    int t = threadIdx.x, lane = t & 63, w = t >> 6;
    int wr = w >> 1, wc = w & 1;
    int l15 = lane & 15, lg = lane >> 4;
    int lr = lane >> 2, lc = (lane & 3) << 3;
    f32x4 acc[4][NI] = {};

    const bf16* Ab = A + (size_t)(m0 + lr) * K + lc;
    const bf16* Bb = Bt + (size_t)(n0 + lr) * K + lc;

    for (int kb = 0; kb < K; kb += BK) {
        __syncthreads();
#pragma unroll
        for (int i = 0; i < 2; i++) {
            int c = w * 2 + i;
            gload_lds16(Ab + (size_t)(c * 16) * K + kb, &As[c * 512]);
        }
#pragma unroll
        for (int i = 0; i < NB; i++) {
            int c = w * NB + i;
            gload_lds16(Bb + (size_t)(c * 16) * K + kb, &Bs[c * 512]);
        }
        __syncthreads();
        bf16x8 af[4], bfr[NI];
#pragma unroll
        for (int i = 0; i < 4; i++)
            af[i] = *(const bf16x8*)&As[(wr * 64 + i * 16 + l15) * BK + lg * 8];
#pragma unroll
        for (int i = 0; i < NI; i++)
            bfr[i] = *(const bf16x8*)&Bs[(wc * WN + i * 16 + l15) * BK + lg * 8];
#pragma unroll
        for (int mi = 0; mi < 4; mi++)
#pragma unroll
            for (int ni = 0; ni < NI; ni++)
                acc[mi][ni] = __builtin_amdgcn_mfma_f32_16x16x32_bf16(af[mi], bfr[ni], acc[mi][ni], 0, 0, 0);
    }

#pragma unroll
    for (int mi = 0; mi < 4; mi++) {
#pragma unroll
        for (int ni = 0; ni < NI; ni++) {
            int col = n0 + wc * WN + ni * 16 + l15;
            float bsv = bias[col];
#pragma unroll
            for (int r = 0; r < 4; r++) {
                int row = m0 + wr * 64 + mi * 16 + lg * 4 + r;
                float v = acc[mi][ni][r] + bsv;
                if (SCALEQ && col < 1024) v *= QSCALE;
                size_t idx = (size_t)row * N + col;
                if (MODE == 0) {
                    ((bf16*)Cout)[idx] = (bf16)v;
                } else if (MODE == 1) {
                    float g = 0.5f * v * (1.0f + erff(v * 0.70710678118654752f));
                    ((bf16*)Cout)[idx] = (bf16)g;
                } else {
                    ((float*)Cout)[idx] = v + res[idx];
                }
            }
        }
    }
}

// ---------------------------------------------------------------- flash attention, dual-QK (qk 128), causal
// grid (16, B*H), 256 threads = 4 waves, wave w owns 16 q-rows. Block j runs q-tiles
// {31-j, j} sequentially -> constant work per block. Q prescaled by QSCALE -> exp2 softmax.
__global__ __launch_bounds__(256, 4) void flash_attn(const bf16* __restrict__ QKV,
                                                     const bf16* __restrict__ QsKs,
                                                     bf16* __restrict__ O) {
    __shared__ __align__(16) bf16 Klds[64 * 128];   // XOR-swizzled: idx ^= (row&7)<<3
    __shared__ __align__(16) bf16 Vt[64][72];       // [d][k], rotated conflict-free writes
    __shared__ __align__(16) bf16 Plds[4][16][36];  // per-wave P tile [q][k32]

    int bh = blockIdx.y;
    int b = bh >> 4, h = bh & 15;
    int t = threadIdx.x;
    int w = t >> 6, lane = t & 63;
    int l15 = lane & 15, lg = lane >> 4;

    int krow = t >> 4;
    int kdd = (t & 15) << 3;
    int vr = t >> 3, j0 = t & 7;

    const bf16* kcb = QKV + (size_t)(b * T_SEQ) * S1 + 1024 + h * DHEAD;
    const bf16* ksb = QsKs + (size_t)(b * T_SEQ) * S2 + 1024 + h * DHEAD;
    const bf16* vb  = QKV + (size_t)(b * T_SEQ) * S1 + 2048 + h * DHEAD + j0 * 8;
    const bf16* ksrc = (kdd < 64) ? (kcb + kdd) : (ksb + kdd - 64);
    size_t kstride = (kdd < 64) ? S1 : S2;

    bf16x8 kreg[4], vreg[2];
#pragma unroll
    for (int i = 0; i < 4; i++) kreg[i] = *(const bf16x8*)(ksrc + (size_t)(i * 16 + krow) * kstride);
#pragma unroll
    for (int i = 0; i < 2; i++) vreg[i] = *(const bf16x8*)(vb + (size_t)(i * 32 + vr) * S1);

    for (int p = 0; p < 2; ++p) {
        int jj = p ? blockIdx.x : (31 - blockIdx.x);
        int q0 = jj * 64;
        int qw = q0 + w * 16;
        int qg = qw + l15;

        size_t qrow = (size_t)(b * T_SEQ + qg);
        const bf16* qcp = QKV + qrow * S1 + h * DHEAD;
        const bf16* qsp = QsKs + qrow * S2 + h * DHEAD;
        bf16x8 qf[4];
#pragma unroll
        for (int c = 0; c < 2; c++) {
            qf[c]     = *(const bf16x8*)(qcp + c * 32 + lg * 8);
            qf[2 + c] = *(const bf16x8*)(qsp + c * 32 + lg * 8);
        }

        float m_run = -1e30f, l_part = 0.0f;
        f32x4 acc[4] = {};
        int nt = q0 / 64 + 1;

        for (int it = 0; it < nt; ++it) {
            __syncthreads();
#pragma unroll
            for (int i = 0; i < 4; i++) {
                int row = i * 16 + krow;
                int idx = ((row << 7) + kdd) ^ ((row & 7) << 3);
                *(bf16x8*)&Klds[idx] = kreg[i];
            }
#pragma unroll
            for (int i = 0; i < 2; i++) {
                int r = i * 32 + vr;
#pragma unroll
                for (int e = 0; e < 8; e++) {
                    int j = (e + j0) & 7;
                    Vt[j0 * 8 + j][r] = vreg[i][j];
                }
            }
            __syncthreads();
            int kn = (it + 1 < nt) ? (it + 1) * 64 : 0;
#pragma unroll
            for (int i = 0; i < 4; i++) kreg[i] = *(const bf16x8*)(ksrc + (size_t)(kn + i * 16 + krow) * kstride);
#pragma unroll
            for (int i = 0; i < 2; i++) vreg[i] = *(const bf16x8*)(vb + (size_t)(kn + i * 32 + vr) * S1);

            int kb = it * 64;
#pragma unroll
            for (int sub = 0; sub < 2; sub++) {
                int kk = kb + sub * 32;
                if (kk > qw + 15) break;
                f32x4 st[2];
                __builtin_amdgcn_s_setprio(1);
#pragma unroll
                for (int tt = 0; tt < 2; tt++) {
                    f32x4 z = {};
#pragma unroll
                    for (int c = 0; c < 4; c++) {
                        int row = sub * 32 + tt * 16 + l15;
                        int idx = ((row << 7) + c * 32 + lg * 8) ^ ((row & 7) << 3);
                        bf16x8 kf = *(const bf16x8*)&Klds[idx];
                        z = __builtin_amdgcn_mfma_f32_16x16x32_bf16(kf, qf[c], z, 0, 0, 0);
                    }
                    st[tt] = z;
                }
                __builtin_amdgcn_s_setprio(0);
                float s[8], lm = -1e30f;
                if (kk + 31 <= qw) {
#pragma unroll
                    for (int tt = 0; tt < 2; tt++)
#pragma unroll
                        for (int r = 0; r < 4; r++) {
                            float sv = st[tt][r];
                            s[tt * 4 + r] = sv;
                            lm = fmaxf(lm, sv);
                        }
                } else {
#pragma unroll
                    for (int tt = 0; tt < 2; tt++)
#pragma unroll
                        for (int r = 0; r < 4; r++) {
                            int kgl = kk + tt * 16 + lg * 4 + r;
                            float sv = st[tt][r];
                            if (kgl > qg) sv = -1e30f;
                            s[tt * 4 + r] = sv;
                            lm = fmaxf(lm, sv);
                        }
                }
                if (__any(lm > m_run + 11.5f)) {
                    float rm = lm;
                    rm = fmaxf(rm, __shfl_xor(rm, 16));
                    rm = fmaxf(rm, __shfl_xor(rm, 32));
                    float m_new = fmaxf(m_run, rm);
                    float sc = exp2f(m_run - m_new);
                    l_part *= sc;
#pragma unroll
                    for (int r = 0; r < 4; r++) {
                        float oscr = __shfl(sc, lg * 4 + r);
#pragma unroll
                        for (int dt = 0; dt < 4; dt++) acc[dt][r] *= oscr;
                    }
                    m_run = m_new;
                }
                float pv[8];
#pragma unroll
                for (int j = 0; j < 8; j++) { pv[j] = exp2f(s[j] - m_run); l_part += pv[j]; }
                bf16x4 pk0, pk1;
#pragma unroll
                for (int r = 0; r < 4; r++) { pk0[r] = (bf16)pv[r]; pk1[r] = (bf16)pv[4 + r]; }
                *(bf16x4*)&Plds[w][l15][lg * 4] = pk0;
                *(bf16x4*)&Plds[w][l15][16 + lg * 4] = pk1;
                asm volatile("s_waitcnt lgkmcnt(0)" ::: "memory");
                __builtin_amdgcn_sched_barrier(0);
                bf16x8 paf = *(const bf16x8*)&Plds[w][l15][lg * 8];
                __builtin_amdgcn_s_setprio(1);
#pragma unroll
                for (int dt = 0; dt < 4; dt++) {
                    bf16x8 vf = *(const bf16x8*)&Vt[dt * 16 + l15][sub * 32 + lg * 8];
                    acc[dt] = __builtin_amdgcn_mfma_f32_16x16x32_bf16(paf, vf, acc[dt], 0, 0, 0);
                }
                __builtin_amdgcn_s_setprio(0);
            }
        }

        float l = l_part;
        l += __shfl_xor(l, 16);
        l += __shfl_xor(l, 32);
        float linv = 1.0f / l;
#pragma unroll
        for (int r = 0; r < 4; r++) {
            float li = __shfl(linv, lg * 4 + r);
            size_t orow = (size_t)(b * T_SEQ + qw + lg * 4 + r);
#pragma unroll
            for (int dt = 0; dt < 4; dt++)
                O[orow * DMODEL + h * DHEAD + dt * 16 + l15] = (bf16)(acc[dt][r] * li);
        }
    }
}

// ---------------------------------------------------------------- launch
extern "C" void kernel_launch(void* const* d_in, const int* in_sizes, int n_in,
                              void* d_out, int out_size, void* d_ws, size_t ws_size,
                              hipStream_t stream) {
    const float* x = (const float*)d_in[0];
    const float* pos = (const float*)d_in[1];
    const float* Wqc = (const float*)d_in[2];  const float* bqc = (const float*)d_in[3];
    const float* Wkc = (const float*)d_in[4];  const float* bkc = (const float*)d_in[5];
    const float* Wqs = (const float*)d_in[6];  const float* bqs = (const float*)d_in[7];
    const float* Wks = (const float*)d_in[8];  const float* bks = (const float*)d_in[9];
    const float* Wv  = (const float*)d_in[10]; const float* bv  = (const float*)d_in[11];
    const float* Wo  = (const float*)d_in[12]; const float* bo  = (const float*)d_in[13];
    const float* ln1w = (const float*)d_in[14]; const float* ln1b = (const float*)d_in[15];
    const float* ln2w = (const float*)d_in[16]; const float* ln2b = (const float*)d_in[17];
    const float* Wf1 = (const float*)d_in[18]; const float* bf1 = (const float*)d_in[19];
    const float* Wf2 = (const float*)d_in[20]; const float* bf2 = (const float*)d_in[21];
    float* out = (float*)d_out;

    char* wsp = (char*)d_ws;
    size_t off = 0;
    auto alloc = [&](size_t bytes) { void* p = wsp + off; off += (bytes + 255) & ~(size_t)255; return p; };
    const size_t DD = (size_t)DMODEL * DMODEL;
    const size_t RD = (size_t)NROWS * DMODEL;
    bf16* Wcat1 = (bf16*)alloc(3 * DD * 2);
    bf16* Wcat2 = (bf16*)alloc(2 * DD * 2);
    bf16* WoT  = (bf16*)alloc(DD * 2);
    bf16* Wf1T = (bf16*)alloc((size_t)DMODEL * DFFN * 2);
    bf16* Wf2T = (bf16*)alloc((size_t)DMODEL * DFFN * 2);
    float* bc1 = (float*)alloc(3 * DMODEL * 4);
    float* bc2 = (float*)alloc(2 * DMODEL * 4);
    bf16* hb   = (bf16*)alloc(RD * 2);
    bf16* posb = (bf16*)alloc(RD * 2);
    bf16* C1   = (bf16*)alloc((size_t)NROWS * S1 * 2);
    bf16* C2   = (bf16*)alloc((size_t)NROWS * S2 * 2);
    bf16* Ab   = (bf16*)alloc(RD * 2);
    float* x2  = (float*)alloc(RD * 4);
    bf16* h2b  = (bf16*)alloc(RD * 2);
    bf16* gb   = (bf16*)alloc((size_t)NROWS * DFFN * 2);

    TP6 tp;
    tp.src[0] = Wqc; tp.dst[0] = Wcat1;
    tp.src[1] = Wkc; tp.dst[1] = Wcat1 + DD;
    tp.src[2] = Wv;  tp.dst[2] = Wcat1 + 2 * DD;
    tp.src[3] = Wqs; tp.dst[3] = Wcat2;
    tp.src[4] = Wks; tp.dst[4] = Wcat2 + DD;
    tp.src[5] = Wo;  tp.dst[5] = WoT;
    transpose6<<<dim3(32, 32, 6), 256, 0, stream>>>(tp);
    transpose_f32_to_bf16<<<dim3(DFFN / 32, DMODEL / 32), 256, 0, stream>>>(Wf1, Wf1T, DMODEL, DFFN);
    transpose_f32_to_bf16<<<dim3(DMODEL / 32, DFFN / 32), 256, 0, stream>>>(Wf2, Wf2T, DFFN, DMODEL);
    concat_bias3<<<12, 256, 0, stream>>>(bqc, bkc, bv, bc1, 3 * DMODEL);
    concat_bias3<<<8, 256, 0, stream>>>(bqs, bks, bqs, bc2, 2 * DMODEL);

    layernorm_bf16<<<NROWS, 256, 0, stream>>>(x, ln1w, ln1b, hb);
    cast_f32_bf16<<<(RD / 4 + 255) / 256, 256, 0, stream>>>(pos, posb, RD / 4);

    // fused projections (8-phase 256^2; Q cols prescaled by QSCALE)
    gemm_256<0, 1><<<dim3(S1 / 256, NROWS / 256), 512, 0, stream>>>(hb, Wcat1, bc1, C1, NROWS, S1, DMODEL);
    gemm_256<0, 1><<<dim3(S2 / 256, NROWS / 256), 512, 0, stream>>>(posb, Wcat2, bc2, C2, NROWS, S2, DMODEL);

    // flash attention
    flash_attn<<<dim3(16, NBATCH * NHEAD), 256, 0, stream>>>(C1, C2, Ab);

    // Wo + residual -> x2 (f32)
    gemm_glds<64, 2, 0><<<dim3(DMODEL / 64, NROWS / 128), 256, 0, stream>>>(Ab, WoT, bo, x, x2, NROWS, DMODEL, DMODEL);

    layernorm_bf16<<<NROWS, 256, 0, stream>>>(x2, ln2w, ln2b, h2b);

    // FFN1 + GELU (8-phase 256^2)
    gemm_256<1, 0><<<dim3(DFFN / 256, NROWS / 256), 512, 0, stream>>>(h2b, Wf1T, bf1, gb, NROWS, DFFN, DMODEL);

    // FFN2 + residual -> out (f32)
    gemm_glds<64, 2, 0><<<dim3(DMODEL / 64, NROWS / 128), 256, 0, stream>>>(gb, Wf2T, bf2, x2, out, NROWS, DMODEL, DFFN);
}